// Round 11
// baseline (283.026 us; speedup 1.0000x reference)
//
#include <hip/hip_runtime.h>

// Problem dims (fixed)
#define BB   4
#define LQ   1024
#define LK   2048
#define D1   1024
#define D2   1280

typedef unsigned short u16;
typedef __attribute__((ext_vector_type(8))) short   short8;   // 8 bf16 = 4 VGPRs
typedef __attribute__((ext_vector_type(4))) float   floatx4;  // MFMA accum

__device__ __forceinline__ u16 f2bf(float f) {
    unsigned u = __float_as_uint(f);
    unsigned r = (u + 0x7FFFu + ((u >> 16) & 1u)) >> 16;   // RNE
    return (u16)r;
}

// async global->LDS, 16B per lane; LDS dest = wave-uniform base + lane*16
__device__ __forceinline__ void gl_lds16(const void* g, void* l) {
    __builtin_amdgcn_global_load_lds(
        (const __attribute__((address_space(1))) unsigned int*)g,
        (__attribute__((address_space(3))) unsigned int*)l, 16, 0, 0);
}

// ---------------------------------------------------------------------------
// Batched fp32 -> bf16 cast: 6 tensors, ONE launch. R11: paired quads ->
// 2x float4 loads feed ONE 16B short8 store (R10 showed 8B stores held the
// kernel at 2.3 TB/s; m146-style 16B stores are the BW sweet spot).
// Segment quad-counts are all even -> a pair never straddles a boundary.
// Also zeroes the 4096-float rowsum array (blocks 0..15).
// ---------------------------------------------------------------------------
struct CastDesc {
    const float* src[6];
    u16*         dst[6];
    long         end[6];      // cumulative end in QUADS (4 elems)
};

__global__ __launch_bounds__(256) void cast6_kernel(CastDesc d, long total_pairs,
                                                    float* __restrict__ rs0)
{
    if (blockIdx.x < 16)
        rs0[blockIdx.x * 256 + threadIdx.x] = 0.f;   // 16*256 = 4096 = BB*LQ

    const long base = (long)blockIdx.x * 1024 + threadIdx.x;
    const float4* sp[4];
    u16*          dp[4];
    bool          ok[4];
    #pragma unroll
    for (int u = 0; u < 4; ++u) {
        const long gi = base + u * 256;              // pair index (8 elems)
        ok[u] = (gi < total_pairs);
        if (ok[u]) {
            int s = 0;
            while (gi >= (d.end[s] >> 1)) ++s;       // 6 segments, short loop
            const long start = (s == 0) ? 0 : (d.end[s - 1] >> 1);
            const long q = gi - start;
            sp[u] = (const float4*)(d.src[s] + q * 8);
            dp[u] = d.dst[s] + q * 8;
        }
    }
    float4 va[4], vb[4];
    #pragma unroll
    for (int u = 0; u < 4; ++u)
        if (ok[u]) { va[u] = sp[u][0]; vb[u] = sp[u][1]; }  // 8 loads in flight
    #pragma unroll
    for (int u = 0; u < 4; ++u) {
        if (ok[u]) {
            short8 o;
            o[0] = (short)f2bf(va[u].x); o[1] = (short)f2bf(va[u].y);
            o[2] = (short)f2bf(va[u].z); o[3] = (short)f2bf(va[u].w);
            o[4] = (short)f2bf(vb[u].x); o[5] = (short)f2bf(vb[u].y);
            o[6] = (short)f2bf(vb[u].z); o[7] = (short)f2bf(vb[u].w);
            *(short8*)dp[u] = o;                     // ONE 16B store
        }
    }
}

// ---------------------------------------------------------------------------
// bf16 MFMA GEMM, operands in [rows][K] layout (B is N x K, i.e. x @ W^T):
//   C[bz][m][n] = epi( sum_k A[bz][m][k] * B[bz][n][k] )
// 128 x BN tile (BN=128 or 64), BK=64, 256 threads = 4 waves (2x2), 16x16x32
// MFMA, global_load_lds(16B) staging, XOR-swizzled LDS (R9: conflicts -> 0),
// XCD-aware flattened grid (R9: FETCH ~= unique bytes). ny % 8 == 0.
//
// Epilogues:
//   EPI_F32_BIAS : fp32 out + bias (out-proj)
//   EPI_KV       : z<BB -> K-proj row-major bf16+bias; z>=BB -> V-proj
//                  transposed bf16+bias2 (MUST be z-batched -- R5/R6 bug)
//   EPI_EXP      : E = bf16(exp(acc*scale)) row-major + atomic per-row sums
//                  (fused softmax part 1; no max-subtract needed, |s|<~6)
//   EPI_ROWSCALE : bf16(acc / rowsum[row]) (fused softmax part 2, ctx GEMM)
// ---------------------------------------------------------------------------
enum { EPI_F32_BIAS, EPI_KV, EPI_EXP, EPI_ROWSCALE };

template <int BN, int EPI>
__global__ __launch_bounds__(256, 2) void mm_bf16(
    const u16* __restrict__ A, const u16* __restrict__ B,
    void* __restrict__ C, const float* __restrict__ bias,
    int nx, int Kd, int lda, int ldb, int ldc,
    long sA, long sB, long sC, float scale,
    const u16* __restrict__ A2, const u16* __restrict__ B2,
    void* __restrict__ C2, const float* __restrict__ bias2,
    int ldc2, long sC2, float* __restrict__ rsum)
{
    constexpr int NJ  = BN / 32;     // j-fragments per wave (4 or 2)
    constexpr int NBI = BN / 32;     // B staging issues per wave

    __shared__ u16 As[128 * 64];     // [m][k] swizzled, 64 k/row = 16 KB
    __shared__ u16 Bs[BN * 64];      // [n][k] swizzled

    // ---- XCD-aware decode of flattened grid.x
    const int u    = blockIdx.x;
    const int rest = u >> 3;
    const int bx   = rest % nx;
    const int by   = (u & 7) + 8 * (rest / nx);

    const int  bz  = blockIdx.z;
    const bool isV = (EPI == EPI_KV) && (bz >= BB);
    const int  b   = isV ? bz - BB : bz;

    const u16* Ab = (isV ? A2 : A) + (long)b * sA + (long)by * 128 * lda;
    const u16* Bb = (isV ? B2 : B) + (long)b * sB + (long)bx * BN  * ldb;

    const int t    = threadIdx.x;
    const int w    = t >> 6;              // wave 0..3
    const int l    = t & 63;
    const int l16  = l & 15;
    const int quad = l >> 4;
    const int wm   = (w >> 1) * 64;       // wave origin in block tile
    const int wn   = (w & 1) * (BN / 2);

    floatx4 acc[4][NJ];
    #pragma unroll
    for (int i = 0; i < 4; ++i)
        #pragma unroll
        for (int j = 0; j < NJ; ++j)
            acc[i][j] = (floatx4){0.f, 0.f, 0.f, 0.f};

    for (int k0 = 0; k0 < Kd; k0 += 64) {
        // ---- stage A (128x64 = 16KB) and B (BNx64), XOR-swizzled source
        #pragma unroll
        for (int c = 0; c < 4; ++c) {
            const int idx = (w * 4 + c) * 64 + l;    // 0..1023 = slot
            const int mr  = idx >> 3;                // row
            const int kq  = (idx & 7) ^ (mr & 7);    // global chunk for slot
            gl_lds16(Ab + (long)mr * lda + k0 + kq * 8, (char*)As + (w * 4 + c) * 1024);
        }
        #pragma unroll
        for (int c = 0; c < NBI; ++c) {
            const int idx = (w * NBI + c) * 64 + l;
            const int mr  = idx >> 3;
            const int kq  = (idx & 7) ^ (mr & 7);
            gl_lds16(Bb + (long)mr * ldb + k0 + kq * 8, (char*)Bs + (w * NBI + c) * 1024);
        }
        __syncthreads();

        // ---- 2 x K=32 MFMA steps; fragment chunk = (q*4+quad)^(l&7)
        #pragma unroll
        for (int q = 0; q < 2; ++q) {
            const int sc = ((q * 4 + quad) ^ (l & 7)) * 8;   // swizzled elem off
            short8 af[4], bfr[NJ];
            #pragma unroll
            for (int i = 0; i < 4; ++i)
                af[i]  = *(const short8*)(As + (wm + i * 16 + l16) * 64 + sc);
            #pragma unroll
            for (int j = 0; j < NJ; ++j)
                bfr[j] = *(const short8*)(Bs + (wn + j * 16 + l16) * 64 + sc);
            #pragma unroll
            for (int i = 0; i < 4; ++i)
                #pragma unroll
                for (int j = 0; j < NJ; ++j)
                    acc[i][j] = __builtin_amdgcn_mfma_f32_16x16x32_bf16(
                        af[i], bfr[j], acc[i][j], 0, 0, 0);
        }
        __syncthreads();
    }

    // ---- epilogue: C/D layout col = lane&15, row = quad*4 + reg
    const int mb = by * 128 + wm;
    const int nb = bx * BN  + wn;

    if (EPI == EPI_F32_BIAS) {
        float* Cp = (float*)C + (long)bz * sC;
        #pragma unroll
        for (int i = 0; i < 4; ++i)
            #pragma unroll
            for (int j = 0; j < NJ; ++j) {
                const int col  = nb + j * 16 + l16;
                const int row0 = mb + i * 16 + quad * 4;
                const float bs = bias[col];
                #pragma unroll
                for (int r = 0; r < 4; ++r)
                    Cp[(long)(row0 + r) * ldc + col] = acc[i][j][r] + bs;
            }
    } else if (EPI == EPI_KV) {
        if (!isV) {        // K-proj: row-major bf16 + bias
            u16* Cp = (u16*)C + (long)b * sC;
            #pragma unroll
            for (int i = 0; i < 4; ++i)
                #pragma unroll
                for (int j = 0; j < NJ; ++j) {
                    const int col  = nb + j * 16 + l16;
                    const int row0 = mb + i * 16 + quad * 4;
                    const float bs = bias[col];
                    #pragma unroll
                    for (int r = 0; r < 4; ++r)
                        Cp[(long)(row0 + r) * ldc + col] = f2bf(acc[i][j][r] + bs);
                }
        } else {           // V-proj: transposed store C2^T[col][row0..+3]
            u16* Cp = (u16*)C2 + (long)b * sC2;
            #pragma unroll
            for (int i = 0; i < 4; ++i)
                #pragma unroll
                for (int j = 0; j < NJ; ++j) {
                    const int col  = nb + j * 16 + l16;
                    const int row0 = mb + i * 16 + quad * 4;
                    const float bs = bias2[col];
                    const floatx4 v = acc[i][j];
                    ushort4 pk;
                    pk.x = f2bf(v[0] + bs); pk.y = f2bf(v[1] + bs);
                    pk.z = f2bf(v[2] + bs); pk.w = f2bf(v[3] + bs);
                    *(ushort4*)(Cp + (long)col * ldc2 + row0) = pk;
                }
        }
    } else if (EPI == EPI_EXP) {
        // E = bf16(exp(acc*scale)); accumulate per-row sums -> atomicAdd
        u16* Cp = (u16*)C + (long)bz * sC;
        float lsum[4][4];
        #pragma unroll
        for (int i = 0; i < 4; ++i)
            #pragma unroll
            for (int r = 0; r < 4; ++r)
                lsum[i][r] = 0.f;
        #pragma unroll
        for (int i = 0; i < 4; ++i)
            #pragma unroll
            for (int j = 0; j < NJ; ++j) {
                const int col  = nb + j * 16 + l16;
                const int row0 = mb + i * 16 + quad * 4;
                #pragma unroll
                for (int r = 0; r < 4; ++r) {
                    const float e = __expf(acc[i][j][r] * scale);
                    Cp[(long)(row0 + r) * ldc + col] = f2bf(e);
                    lsum[i][r] += e;
                }
            }
        // reduce across the 16 l16-lanes of each quad, one atomic per row
        float* rp = rsum + (long)bz * LQ;
        #pragma unroll
        for (int i = 0; i < 4; ++i)
            #pragma unroll
            for (int r = 0; r < 4; ++r) {
                float s = lsum[i][r];
                s += __shfl_xor(s, 1);
                s += __shfl_xor(s, 2);
                s += __shfl_xor(s, 4);
                s += __shfl_xor(s, 8);
                if (l16 == 0)
                    atomicAdd(rp + mb + i * 16 + quad * 4 + r, s);
            }
    } else { // EPI_ROWSCALE: bf16(acc / rowsum[row])
        u16* Cp = (u16*)C + (long)bz * sC;
        const float* rp = rsum + (long)bz * LQ;
        #pragma unroll
        for (int i = 0; i < 4; ++i) {
            const int row0 = mb + i * 16 + quad * 4;
            float inv[4];
            #pragma unroll
            for (int r = 0; r < 4; ++r)
                inv[r] = 1.0f / rp[row0 + r];
            #pragma unroll
            for (int j = 0; j < NJ; ++j) {
                const int col = nb + j * 16 + l16;
                #pragma unroll
                for (int r = 0; r < 4; ++r)
                    Cp[(long)(row0 + r) * ldc + col] = f2bf(acc[i][j][r] * inv[r]);
            }
        }
    }
}

// ---------------------------------------------------------------------------
extern "C" void kernel_launch(void* const* d_in, const int* in_sizes, int n_in,
                              void* d_out, int out_size, void* d_ws, size_t ws_size,
                              hipStream_t stream)
{
    const float* Q  = (const float*)d_in[0];
    const float* K  = (const float*)d_in[1];
    const float* V  = (const float*)d_in[2];
    const float* Wk = (const float*)d_in[3];
    const float* bk = (const float*)d_in[4];
    const float* Wv = (const float*)d_in[5];
    const float* bv = (const float*)d_in[6];
    const float* Wo = (const float*)d_in[7];
    const float* bo = (const float*)d_in[8];
    float* out = (float*)d_out;

    // Workspace layout (max extent 94.4 MB + 16 KB <= 100.6 MB proven):
    //   Kbf  [0.0, 22.0)M   dead after KV-proj; E aliases its head
    //   Vbf  [22.0, 44.0)M  dead after KV-proj
    //   Qbf  [44.0, 52.4)M  dead after scores
    //   Wkbf/Wvbf/Wobf [52.8, 60.4)M
    //   Kp   [60.8, 77.6)M  dead after scores; Ctx aliases it
    //   VpT  [77.6, 94.4)M
    //   E    [0.0, 16.8)M   bf16 exp-scores (aliases dead Kbf)
    //   rsum [94.4M, +16K)  fp32 per-row exp sums
    char* ws = (char*)d_ws;
    u16*   Kbf  = (u16*)(ws);
    u16*   Vbf  = (u16*)(ws + 22020096);
    u16*   Qbf  = (u16*)(ws + 44040192);
    u16*   Wkbf = (u16*)(ws + 52828160);
    u16*   Wvbf = (u16*)(ws + 55574528);
    u16*   Wobf = (u16*)(ws + 58320896);
    u16*   Kp   = (u16*)(ws + 60817408);
    u16*   VpT  = (u16*)(ws + 77594624);
    u16*   E    = (u16*)(ws);
    float* rsum = (float*)(ws + 94371840);
    u16*   Ctx  = Kp;

    const float inv_sqrt_d = 0.03125f;   // 1/sqrt(1024)

    // ---- one batched cast launch (also zeroes rsum)
    CastDesc cd;
    cd.src[0] = K;  cd.dst[0] = Kbf;
    cd.src[1] = V;  cd.dst[1] = Vbf;
    cd.src[2] = Q;  cd.dst[2] = Qbf;
    cd.src[3] = Wk; cd.dst[3] = Wkbf;
    cd.src[4] = Wv; cd.dst[4] = Wvbf;
    cd.src[5] = Wo; cd.dst[5] = Wobf;
    long acc = 0;
    const long sizes[6] = {(long)BB*LK*D2, (long)BB*LK*D2, (long)BB*LQ*D1,
                           (long)D1*D2, (long)D1*D2, (long)D1*D1};
    for (int i = 0; i < 6; ++i) { acc += sizes[i] / 4; cd.end[i] = acc; }
    const long total_pairs = acc / 2;
    cast6_kernel<<<dim3((unsigned)((total_pairs + 1023) / 1024)), 256, 0, stream>>>(
        cd, total_pairs, rsum);

    // ---- merged K/V projections, z-batched, grid.z = 8, nx=8, ny=16
    mm_bf16<128, EPI_KV><<<dim3((D1/128)*(LK/128), 1, 2*BB), 256, 0, stream>>>(
        Kbf, Wkbf, Kp, bk, D1/128, D2, D2, D2, D1,
        (long)LK*D2, 0, (long)LK*D1, 1.0f,
        Vbf, Wvbf, VpT, bv, LK, (long)D1*LK, nullptr);

    // ---- fused scores+exp: E[b][q][k] = exp(Q@Kp^T / 32), rsum += row sums
    mm_bf16<128, EPI_EXP><<<dim3((LK/128)*(LQ/128), 1, BB), 256, 0, stream>>>(
        Qbf, Kp, E, nullptr, LK/128, D1, D1, D1, LK,
        (long)LQ*D1, (long)LK*D1, (long)LQ*LK, inv_sqrt_d,
        nullptr, nullptr, nullptr, nullptr, 0, 0, rsum);

    // ---- context with fused normalization: Ctx = (E @ VpT^T) / rsum[row]
    mm_bf16<64, EPI_ROWSCALE><<<dim3((D1/64)*(LQ/128), 1, BB), 256, 0, stream>>>(
        E, VpT, Ctx, nullptr, D1/64, LK, LK, LK, D1,
        (long)LQ*LK, (long)D1*LK, (long)LQ*D1, 1.0f,
        nullptr, nullptr, nullptr, nullptr, 0, 0, rsum);

    // ---- output: out = Ctx @ Wo^T + bo  (fp32, fold into M OK, nx=16, ny=32)
    mm_bf16<64, EPI_F32_BIAS><<<dim3((D1/64)*((BB*LQ)/128), 1, 1), 256, 0, stream>>>(
        Ctx, Wobf, out, bo, D1/64, D1, D1, D1, D1, 0, 0, 0, 1.0f,
        nullptr, nullptr, nullptr, nullptr, 0, 0, nullptr);
}

// Round 12
// 272.299 us; speedup vs baseline: 1.0394x; 1.0394x over previous
//
#include <hip/hip_runtime.h>

// Problem dims (fixed)
#define BB   4
#define LQ   1024
#define LK   2048
#define D1   1024
#define D2   1280

typedef unsigned short u16;
typedef __attribute__((ext_vector_type(8))) short   short8;   // 8 bf16 = 4 VGPRs
typedef __attribute__((ext_vector_type(4))) float   floatx4;  // MFMA accum

__device__ __forceinline__ u16 f2bf(float f) {
    unsigned u = __float_as_uint(f);
    unsigned r = (u + 0x7FFFu + ((u >> 16) & 1u)) >> 16;   // RNE
    return (u16)r;
}

// async global->LDS, 16B per lane; LDS dest = wave-uniform base + lane*16
__device__ __forceinline__ void gl_lds16(const void* g, void* l) {
    __builtin_amdgcn_global_load_lds(
        (const __attribute__((address_space(1))) unsigned int*)g,
        (__attribute__((address_space(3))) unsigned int*)l, 16, 0, 0);
}

// ---------------------------------------------------------------------------
// Batched fp32 -> bf16 cast: 6 tensors, ONE launch. R12: REVERTED to the
// R7-measured-fastest form (1 quad/thread, 44 us). R8's 4-quad and R11's
// paired-16B-store variants both measured SLOWER (50/53 us) -- the compiler
// serialized the extra in-flight loads (VGPR_Count 16/24).
// Also zeroes the 4096-float rowsum array (blocks 0..15).
// ---------------------------------------------------------------------------
struct CastDesc {
    const float* src[6];
    u16*         dst[6];
    long         end[6];      // cumulative end in QUADS (4 elems)
};

__global__ __launch_bounds__(256) void cast6_kernel(CastDesc d, long total_quads,
                                                    float* __restrict__ rs0)
{
    if (blockIdx.x < 16)
        rs0[blockIdx.x * 256 + threadIdx.x] = 0.f;   // 16*256 = 4096 = BB*LQ

    long gi = (long)blockIdx.x * 256 + threadIdx.x;
    if (gi >= total_quads) return;
    int s = 0;
    while (gi >= d.end[s]) ++s;            // 6 segments, short loop
    const long start = (s == 0) ? 0 : d.end[s - 1];
    const long q = gi - start;
    const float4 v = *(const float4*)(d.src[s] + q * 4);
    ushort4 o;
    o.x = f2bf(v.x); o.y = f2bf(v.y); o.z = f2bf(v.z); o.w = f2bf(v.w);
    *(ushort4*)(d.dst[s] + q * 4) = o;
}

// ---------------------------------------------------------------------------
// bf16 MFMA GEMM, operands in [rows][K] layout (B is N x K, i.e. x @ W^T):
//   C[bz][m][n] = epi( sum_k A[bz][m][k] * B[bz][n][k] )
// BM x BN tile, BK=64, 256 threads = 4 waves, 16x16x32 MFMA,
// global_load_lds(16B) staging, XOR-swizzled LDS (R9: conflicts -> 0),
// XCD-aware flattened grid (R9: FETCH ~= unique bytes). ny % 8 == 0.
//
// Wave arrangement (R12): BM=128 -> 2x2 waves of 64 x BN/2 (as before).
//   BM=256 -> 4 waves stacked in M, each 64 x BN (NJ=BN/16): A-fragments
//   become wave-unique, halving LDS fragment-read traffic per unit work
//   (LDS BW is the measured binding resource: 60K cyc of KV-proj's 120K).
//
// Epilogues:
//   EPI_F32_BIAS : fp32 out + bias (out-proj)
//   EPI_KV       : z<BB -> K-proj row-major bf16+bias; z>=BB -> V-proj
//                  transposed bf16+bias2 (MUST be z-batched -- R5/R6 bug)
//   EPI_EXP      : E = bf16(exp(acc*scale)) row-major + atomic per-row sums
//   EPI_ROWSCALE : bf16(acc / rowsum[row]) (fused softmax part 2, ctx GEMM)
// ---------------------------------------------------------------------------
enum { EPI_F32_BIAS, EPI_KV, EPI_EXP, EPI_ROWSCALE };

template <int BM, int BN, int EPI>
__global__ __launch_bounds__(256, 2) void mm_bf16(
    const u16* __restrict__ A, const u16* __restrict__ B,
    void* __restrict__ C, const float* __restrict__ bias,
    int nx, int Kd, int lda, int ldb, int ldc,
    long sA, long sB, long sC, float scale,
    const u16* __restrict__ A2, const u16* __restrict__ B2,
    void* __restrict__ C2, const float* __restrict__ bias2,
    int ldc2, long sC2, float* __restrict__ rsum)
{
    constexpr bool TALL = (BM == 256);
    constexpr int  NJ   = TALL ? (BN / 16) : (BN / 32);  // j-frags per wave
    constexpr int  AISS = BM / 32;    // A staging issues per thread
    constexpr int  NBI  = BN / 32;    // B staging issues per thread

    __shared__ u16 As[BM * 64];      // [m][k] swizzled (16/32 KB)
    __shared__ u16 Bs[BN * 64];      // [n][k] swizzled (8/16 KB)

    // ---- XCD-aware decode of flattened grid.x
    const int u    = blockIdx.x;
    const int rest = u >> 3;
    const int bx   = rest % nx;
    const int by   = (u & 7) + 8 * (rest / nx);

    const int  bz  = blockIdx.z;
    const bool isV = (EPI == EPI_KV) && (bz >= BB);
    const int  b   = isV ? bz - BB : bz;

    const u16* Ab = (isV ? A2 : A) + (long)b * sA + (long)by * BM * lda;
    const u16* Bb = (isV ? B2 : B) + (long)b * sB + (long)bx * BN * ldb;

    const int t    = threadIdx.x;
    const int w    = t >> 6;              // wave 0..3
    const int l    = t & 63;
    const int l16  = l & 15;
    const int quad = l >> 4;
    const int wm   = TALL ? w * 64 : (w >> 1) * 64;   // wave origin in tile
    const int wn   = TALL ? 0      : (w & 1) * (BN / 2);

    floatx4 acc[4][NJ];
    #pragma unroll
    for (int i = 0; i < 4; ++i)
        #pragma unroll
        for (int j = 0; j < NJ; ++j)
            acc[i][j] = (floatx4){0.f, 0.f, 0.f, 0.f};

    for (int k0 = 0; k0 < Kd; k0 += 64) {
        // ---- stage A (BMx64) and B (BNx64), XOR-swizzled source
        #pragma unroll
        for (int c = 0; c < AISS; ++c) {
            const int idx = (w * AISS + c) * 64 + l;  // slot
            const int mr  = idx >> 3;                 // row 0..BM-1
            const int kq  = (idx & 7) ^ (mr & 7);     // global chunk for slot
            gl_lds16(Ab + (long)mr * lda + k0 + kq * 8, (char*)As + (w * AISS + c) * 1024);
        }
        #pragma unroll
        for (int c = 0; c < NBI; ++c) {
            const int idx = (w * NBI + c) * 64 + l;
            const int mr  = idx >> 3;
            const int kq  = (idx & 7) ^ (mr & 7);
            gl_lds16(Bb + (long)mr * ldb + k0 + kq * 8, (char*)Bs + (w * NBI + c) * 1024);
        }
        __syncthreads();

        // ---- 2 x K=32 MFMA steps; fragment chunk = (q*4+quad)^(l&7)
        #pragma unroll
        for (int q = 0; q < 2; ++q) {
            const int sc = ((q * 4 + quad) ^ (l & 7)) * 8;   // swizzled elem off
            short8 af[4], bfr[NJ];
            #pragma unroll
            for (int i = 0; i < 4; ++i)
                af[i]  = *(const short8*)(As + (wm + i * 16 + l16) * 64 + sc);
            #pragma unroll
            for (int j = 0; j < NJ; ++j)
                bfr[j] = *(const short8*)(Bs + (wn + j * 16 + l16) * 64 + sc);
            #pragma unroll
            for (int i = 0; i < 4; ++i)
                #pragma unroll
                for (int j = 0; j < NJ; ++j)
                    acc[i][j] = __builtin_amdgcn_mfma_f32_16x16x32_bf16(
                        af[i], bfr[j], acc[i][j], 0, 0, 0);
        }
        __syncthreads();
    }

    // ---- epilogue: C/D layout col = lane&15, row = quad*4 + reg
    const int mb = by * BM + wm;
    const int nb = bx * BN + wn;

    if (EPI == EPI_F32_BIAS) {
        float* Cp = (float*)C + (long)bz * sC;
        #pragma unroll
        for (int i = 0; i < 4; ++i)
            #pragma unroll
            for (int j = 0; j < NJ; ++j) {
                const int col  = nb + j * 16 + l16;
                const int row0 = mb + i * 16 + quad * 4;
                const float bs = bias[col];
                #pragma unroll
                for (int r = 0; r < 4; ++r)
                    Cp[(long)(row0 + r) * ldc + col] = acc[i][j][r] + bs;
            }
    } else if (EPI == EPI_KV) {
        if (!isV) {        // K-proj: row-major bf16 + bias
            u16* Cp = (u16*)C + (long)b * sC;
            #pragma unroll
            for (int i = 0; i < 4; ++i)
                #pragma unroll
                for (int j = 0; j < NJ; ++j) {
                    const int col  = nb + j * 16 + l16;
                    const int row0 = mb + i * 16 + quad * 4;
                    const float bs = bias[col];
                    #pragma unroll
                    for (int r = 0; r < 4; ++r)
                        Cp[(long)(row0 + r) * ldc + col] = f2bf(acc[i][j][r] + bs);
                }
        } else {           // V-proj: transposed store C2^T[col][row0..+3]
            u16* Cp = (u16*)C2 + (long)b * sC2;
            #pragma unroll
            for (int i = 0; i < 4; ++i)
                #pragma unroll
                for (int j = 0; j < NJ; ++j) {
                    const int col  = nb + j * 16 + l16;
                    const int row0 = mb + i * 16 + quad * 4;
                    const float bs = bias2[col];
                    const floatx4 v = acc[i][j];
                    ushort4 pk;
                    pk.x = f2bf(v[0] + bs); pk.y = f2bf(v[1] + bs);
                    pk.z = f2bf(v[2] + bs); pk.w = f2bf(v[3] + bs);
                    *(ushort4*)(Cp + (long)col * ldc2 + row0) = pk;
                }
        }
    } else if (EPI == EPI_EXP) {
        // E = bf16(exp(acc*scale)); accumulate per-row sums -> atomicAdd
        u16* Cp = (u16*)C + (long)bz * sC;
        float lsum[4][4];
        #pragma unroll
        for (int i = 0; i < 4; ++i)
            #pragma unroll
            for (int r = 0; r < 4; ++r)
                lsum[i][r] = 0.f;
        #pragma unroll
        for (int i = 0; i < 4; ++i)
            #pragma unroll
            for (int j = 0; j < NJ; ++j) {
                const int col  = nb + j * 16 + l16;
                const int row0 = mb + i * 16 + quad * 4;
                #pragma unroll
                for (int r = 0; r < 4; ++r) {
                    const float e = __expf(acc[i][j][r] * scale);
                    Cp[(long)(row0 + r) * ldc + col] = f2bf(e);
                    lsum[i][r] += e;
                }
            }
        // reduce across the 16 l16-lanes of each quad, one atomic per row
        float* rp = rsum + (long)bz * LQ;
        #pragma unroll
        for (int i = 0; i < 4; ++i)
            #pragma unroll
            for (int r = 0; r < 4; ++r) {
                float s = lsum[i][r];
                s += __shfl_xor(s, 1);
                s += __shfl_xor(s, 2);
                s += __shfl_xor(s, 4);
                s += __shfl_xor(s, 8);
                if (l16 == 0)
                    atomicAdd(rp + mb + i * 16 + quad * 4 + r, s);
            }
    } else { // EPI_ROWSCALE: bf16(acc / rowsum[row])
        u16* Cp = (u16*)C + (long)bz * sC;
        const float* rp = rsum + (long)bz * LQ;
        #pragma unroll
        for (int i = 0; i < 4; ++i) {
            const int row0 = mb + i * 16 + quad * 4;
            float inv[4];
            #pragma unroll
            for (int r = 0; r < 4; ++r)
                inv[r] = 1.0f / rp[row0 + r];
            #pragma unroll
            for (int j = 0; j < NJ; ++j) {
                const int col = nb + j * 16 + l16;
                #pragma unroll
                for (int r = 0; r < 4; ++r)
                    Cp[(long)(row0 + r) * ldc + col] = f2bf(acc[i][j][r] * inv[r]);
            }
        }
    }
}

// ---------------------------------------------------------------------------
extern "C" void kernel_launch(void* const* d_in, const int* in_sizes, int n_in,
                              void* d_out, int out_size, void* d_ws, size_t ws_size,
                              hipStream_t stream)
{
    const float* Q  = (const float*)d_in[0];
    const float* K  = (const float*)d_in[1];
    const float* V  = (const float*)d_in[2];
    const float* Wk = (const float*)d_in[3];
    const float* bk = (const float*)d_in[4];
    const float* Wv = (const float*)d_in[5];
    const float* bv = (const float*)d_in[6];
    const float* Wo = (const float*)d_in[7];
    const float* bo = (const float*)d_in[8];
    float* out = (float*)d_out;

    // Workspace layout (max extent 94.4 MB + 16 KB <= 100.6 MB proven):
    //   Kbf  [0.0, 22.0)M   dead after KV-proj; E aliases its head
    //   Vbf  [22.0, 44.0)M  dead after KV-proj
    //   Qbf  [44.0, 52.4)M  dead after scores
    //   Wkbf/Wvbf/Wobf [52.8, 60.4)M
    //   Kp   [60.8, 77.6)M  dead after scores; Ctx aliases it
    //   VpT  [77.6, 94.4)M
    //   E    [0.0, 16.8)M   bf16 exp-scores (aliases dead Kbf)
    //   rsum [94.4M, +16K)  fp32 per-row exp sums
    char* ws = (char*)d_ws;
    u16*   Kbf  = (u16*)(ws);
    u16*   Vbf  = (u16*)(ws + 22020096);
    u16*   Qbf  = (u16*)(ws + 44040192);
    u16*   Wkbf = (u16*)(ws + 52828160);
    u16*   Wvbf = (u16*)(ws + 55574528);
    u16*   Wobf = (u16*)(ws + 58320896);
    u16*   Kp   = (u16*)(ws + 60817408);
    u16*   VpT  = (u16*)(ws + 77594624);
    u16*   E    = (u16*)(ws);
    float* rsum = (float*)(ws + 94371840);
    u16*   Ctx  = Kp;

    const float inv_sqrt_d = 0.03125f;   // 1/sqrt(1024)

    // ---- one batched cast launch (also zeroes rsum)
    CastDesc cd;
    cd.src[0] = K;  cd.dst[0] = Kbf;
    cd.src[1] = V;  cd.dst[1] = Vbf;
    cd.src[2] = Q;  cd.dst[2] = Qbf;
    cd.src[3] = Wk; cd.dst[3] = Wkbf;
    cd.src[4] = Wv; cd.dst[4] = Wvbf;
    cd.src[5] = Wo; cd.dst[5] = Wobf;
    long acc = 0;
    const long sizes[6] = {(long)BB*LK*D2, (long)BB*LK*D2, (long)BB*LQ*D1,
                           (long)D1*D2, (long)D1*D2, (long)D1*D1};
    for (int i = 0; i < 6; ++i) { acc += sizes[i] / 4; cd.end[i] = acc; }
    cast6_kernel<<<dim3((unsigned)((acc + 255) / 256)), 256, 0, stream>>>(cd, acc, rsum);

    // ---- merged K/V projections, 256x128 tiles (R12), z=8, nx=8, ny=8
    mm_bf16<256, 128, EPI_KV><<<dim3((D1/128)*(LK/256), 1, 2*BB), 256, 0, stream>>>(
        Kbf, Wkbf, Kp, bk, D1/128, D2, D2, D2, D1,
        (long)LK*D2, 0, (long)LK*D1, 1.0f,
        Vbf, Wvbf, VpT, bv, LK, (long)D1*LK, nullptr);

    // ---- fused scores+exp: E[b][q][k] = exp(Q@Kp^T / 32), rsum += row sums
    mm_bf16<128, 128, EPI_EXP><<<dim3((LK/128)*(LQ/128), 1, BB), 256, 0, stream>>>(
        Qbf, Kp, E, nullptr, LK/128, D1, D1, D1, LK,
        (long)LQ*D1, (long)LK*D1, (long)LQ*LK, inv_sqrt_d,
        nullptr, nullptr, nullptr, nullptr, 0, 0, rsum);

    // ---- context with fused normalization: Ctx = (E @ VpT^T) / rsum[row]
    mm_bf16<128, 64, EPI_ROWSCALE><<<dim3((D1/64)*(LQ/128), 1, BB), 256, 0, stream>>>(
        E, VpT, Ctx, nullptr, D1/64, LK, LK, LK, D1,
        (long)LQ*LK, (long)D1*LK, (long)LQ*D1, 1.0f,
        nullptr, nullptr, nullptr, nullptr, 0, 0, rsum);

    // ---- output: out = Ctx @ Wo^T + bo  (fp32, fold into M OK, nx=16, ny=32)
    mm_bf16<128, 64, EPI_F32_BIAS><<<dim3((D1/64)*((BB*LQ)/128), 1, 1), 256, 0, stream>>>(
        Ctx, Wobf, out, bo, D1/64, D1, D1, D1, D1, 0, 0, 0, 1.0f,
        nullptr, nullptr, nullptr, nullptr, 0, 0, nullptr);
}